// Round 5
// baseline (127.506 us; speedup 1.0000x reference)
//
#include <hip/hip_runtime.h>
#include <hip/hip_bf16.h>

// Problem constants
#define B_ 8
#define T_ 8192
#define D_ 128
#define S_ 128
#define CK 64
#define NC 128           // T_/CK
#define PAIRROWS 128     // 2 chunks per block
#define NPAIR 64         // pairs per chain
#define NBLK (B_*NPAIR)  // 512
#define XSTR 140         // xb row stride in halfwords (280B; measured 0 bank conflicts)

typedef __attribute__((ext_vector_type(8))) __bf16 bf16x8;
typedef __attribute__((ext_vector_type(4))) float floatx4;

// ws layout (floats)
#define WS_WBF     0                        // 4 mats bf16 (frag-swizzled) = 32768 floats
#define WS_AVEC    32768                    // 128
#define WS_PART    32896                    // u64[NBLK*128] pair aggregates (P,H) = 512KB
#define WS_PARTI   (32896 + 131072)         // u64[NBLK*128] inclusive prefixes = 512KB

__device__ __forceinline__ unsigned short f2bf(float f) {
  __hip_bfloat16 b = __float2bfloat16(f);
  return *(unsigned short*)&b;
}

__device__ __forceinline__ float softplus1(float z) {
  float sp = fmaxf(z, 0.0f) + __logf(1.0f + __expf(-fabsf(z)));
  return fminf(sp, 1.0f);
}

__device__ __forceinline__ unsigned long long part_load(const unsigned long long* p) {
  return __hip_atomic_load(p, __ATOMIC_RELAXED, __HIP_MEMORY_SCOPE_AGENT);
}
__device__ __forceinline__ void part_store(unsigned long long* p, unsigned long long v) {
  __hip_atomic_store(p, v, __ATOMIC_RELAXED, __HIP_MEMORY_SCOPE_AGENT);
}

// ---------------- K0: weights -> bf16 fragment order; zero partials ----------------
// wb[(((m*8+nt)*4+kk)*64 + lane)*8 + e] <- W_m[16nt + (lane&15)][32kk + 8*(lane>>4) + e]
__global__ __launch_bounds__(256) void k0_prep(
    const float* __restrict__ Wdt, const float* __restrict__ WB,
    const float* __restrict__ WC,  const float* __restrict__ Wout,
    const float* __restrict__ logA, float* __restrict__ ws) {
  unsigned short* wb = (unsigned short*)(ws + WS_WBF);
  const float* srcs[4] = {Wdt, WB, WC, Wout};
  int gid = blockIdx.x * 256 + threadIdx.x;   // 0..16383
  if (gid < 8192) {
    int fid = gid;                            // one fragment per thread
    int lane = fid & 63;
    int kk   = (fid >> 6) & 3;
    int nt   = (fid >> 8) & 7;
    int m    = fid >> 11;
    int c = lane & 15, g = lane >> 4;
    const float* src = srcs[m] + (16 * nt + c) * 128 + 32 * kk + 8 * g;
    float4 v0 = *(const float4*)src;
    float4 v1 = *(const float4*)(src + 4);
    unsigned short o[8];
    o[0] = f2bf(v0.x); o[1] = f2bf(v0.y); o[2] = f2bf(v0.z); o[3] = f2bf(v0.w);
    o[4] = f2bf(v1.x); o[5] = f2bf(v1.y); o[6] = f2bf(v1.z); o[7] = f2bf(v1.w);
    *(ushort4*)&wb[fid * 8]     = *(ushort4*)&o[0];
    *(ushort4*)&wb[fid * 8 + 4] = *(ushort4*)&o[4];
  }
  // zero BOTH partials arrays (1 MB total; ws is poisoned 0xAA before every call)
  unsigned long long* part = (unsigned long long*)(ws + WS_PART);
#pragma unroll
  for (int i = 0; i < 8; ++i)
    part[gid + 16384 * i] = 0ull;
  if (blockIdx.x == 0 && threadIdx.x < 128)
    ws[WS_AVEC + threadIdx.x] = -fminf(expf(logA[threadIdx.x]), 10.0f);
}

// fragment load: contiguous 1KB per wave
#define WFRAG(mat, nt, kk) \
  (*(const bf16x8*)&wb[(((((mat) * 8 + (nt)) * 4) + (kk)) * 64 + lane) * 8])

// ---------------- K_MAIN ----------------
// 2 chunks (128 rows) per block, N-split wave ownership: wave w owns states
// 32w..32w+31 for ALL 128 rows (m-tiles mt=0..7). Cross-chunk carry is chained
// in-register by the 8-tile scan. Halves lookback instances+depth, weight L2
// reads, and per-row staging overhead vs 1-chunk blocks.
__global__ __launch_bounds__(256, 2) void k_main(
    const float* __restrict__ x, const float* __restrict__ bdt,
    float* __restrict__ out, float* __restrict__ ws) {
  __shared__ __align__(16) unsigned short xb[PAIRROWS * XSTR]; // x bf16, reused as hT
  __shared__ float x0s[PAIRROWS];                              // x[t,0], reused as y*x0
  __shared__ float yxa[4 * PAIRROWS];                          // per-wave y partials

  const int tid  = threadIdx.x;
  const int bc   = blockIdx.x;       // 0..511
  const int b    = bc & 7;
  const int cpair= bc >> 3;          // 0..63
  const long chunk_t0 = (long)b * T_ + (long)cpair * PAIRROWS;
  const int w    = tid >> 6;
  const int lane = tid & 63;
  const int g    = lane >> 4;
  const int c    = lane & 15;

  float Av2[2], Bd2[2];
#pragma unroll
  for (int ntl = 0; ntl < 2; ++ntl) {
    int s = 32 * w + 16 * ntl + c;
    Av2[ntl] = ws[WS_AVEC + s];
    Bd2[ntl] = bdt[s];
  }

  // ---- stage x -> bf16 LDS (+ x0 fp32) ----
  const float4* x4 = (const float4*)(x + chunk_t0 * D_);
#pragma unroll
  for (int i = 0; i < 16; ++i) {
    int f4 = tid + 256 * i;
    int t  = f4 >> 5;
    int d0 = (f4 & 31) << 2;
    float4 v = x4[f4];
    ushort4 o;
    o.x = f2bf(v.x); o.y = f2bf(v.y); o.z = f2bf(v.z); o.w = f2bf(v.w);
    *(ushort4*)&xb[t * XSTR + d0] = o;
  }
  if (tid < PAIRROWS) x0s[tid] = x[(chunk_t0 + tid) * D_];
  __syncthreads();

  const unsigned short* wb = (const unsigned short*)(ws + WS_WBF);
  unsigned long long* partA = (unsigned long long*)(ws + WS_PART);
  unsigned long long* partI = (unsigned long long*)(ws + WS_PARTI);

  // ---- dt & B GEMMs: A = x rows (8 m-tiles), B = this wave's 2 nt slices ----
  floatx4 A_[2][8], U_[2][8];
#pragma unroll
  for (int ntl = 0; ntl < 2; ++ntl)
#pragma unroll
    for (int mt = 0; mt < 8; ++mt) {
      A_[ntl][mt] = (floatx4){0.f, 0.f, 0.f, 0.f};
      U_[ntl][mt] = (floatx4){0.f, 0.f, 0.f, 0.f};
    }
#pragma unroll
  for (int kk = 0; kk < 4; ++kk) {
    bf16x8 fD0 = WFRAG(0, 2 * w + 0, kk);
    bf16x8 fD1 = WFRAG(0, 2 * w + 1, kk);
    bf16x8 fB0 = WFRAG(1, 2 * w + 0, kk);
    bf16x8 fB1 = WFRAG(1, 2 * w + 1, kk);
#pragma unroll
    for (int mt = 0; mt < 8; ++mt) {
      bf16x8 a = *(const bf16x8*)&xb[(16 * mt + c) * XSTR + 8 * g + 32 * kk];
      A_[0][mt] = __builtin_amdgcn_mfma_f32_16x16x32_bf16(a, fD0, A_[0][mt], 0, 0, 0);
      A_[1][mt] = __builtin_amdgcn_mfma_f32_16x16x32_bf16(a, fD1, A_[1][mt], 0, 0, 0);
      U_[0][mt] = __builtin_amdgcn_mfma_f32_16x16x32_bf16(a, fB0, U_[0][mt], 0, 0, 0);
      U_[1][mt] = __builtin_amdgcn_mfma_f32_16x16x32_bf16(a, fB1, U_[1][mt], 0, 0, 0);
    }
  }

  // ---- elementwise -> a (A_), u (U_) ----
#pragma unroll
  for (int ntl = 0; ntl < 2; ++ntl)
#pragma unroll
    for (int mt = 0; mt < 8; ++mt)
#pragma unroll
      for (int i = 0; i < 4; ++i) {
        float dt = softplus1(A_[ntl][mt][i] + Bd2[ntl]);
        float u  = U_[ntl][mt][i] * dt;
        float la = fmaxf(fminf(dt * Av2[ntl], 0.0f), -0.5f);
        A_[ntl][mt][i] = __expf(la);
        U_[ntl][mt][i] = u;
      }

  // ---- wave-local scan over all 128 rows (8 m-tiles chained in-register) ----
  float PcT[2], HcT[2];
#pragma unroll
  for (int ntl = 0; ntl < 2; ++ntl) {
    float Pc = 1.0f, Hc = 0.0f;   // carry entering current m-tile (from pair start)
#pragma unroll
    for (int mt = 0; mt < 8; ++mt) {
      // intra-lane inclusive over the lane's 4 rows
      float P = A_[ntl][mt][0], H = U_[ntl][mt][0];
#pragma unroll
      for (int i = 1; i < 4; ++i) {
        H = fmaf(H, A_[ntl][mt][i], U_[ntl][mt][i]);
        P = P * A_[ntl][mt][i];
        A_[ntl][mt][i] = P;
        U_[ntl][mt][i] = H;
      }
      // Kogge-Stone over g-segments (16-row tile)
      float Po = __shfl(P, (lane - 16) & 63), Ho = __shfl(H, (lane - 16) & 63);
      if (g >= 1) { H = fmaf(Ho, P, H); P = Po * P; }
      Po = __shfl(P, (lane - 32) & 63); Ho = __shfl(H, (lane - 32) & 63);
      if (g >= 2) { H = fmaf(Ho, P, H); P = Po * P; }
      // tile totals (inclusive over 16 rows) live at g==3
      float Pt = __shfl(P, 48 + c);
      float Ht = __shfl(H, 48 + c);
      // exclusive entering this lane's segment (within tile)
      float Pe = __shfl(P, (lane - 16) & 63), He = __shfl(H, (lane - 16) & 63);
      if (g == 0) { Pe = 1.0f; He = 0.0f; }
      // compose with pair carry entering this tile
      float Hent = fmaf(Pe, Hc, He);
      float Pent = Pe * Pc;
#pragma unroll
      for (int i = 0; i < 4; ++i) {
        U_[ntl][mt][i] = fmaf(A_[ntl][mt][i], Hent, U_[ntl][mt][i]);  // h_local
        A_[ntl][mt][i] = A_[ntl][mt][i] * Pent;                       // cumP
      }
      Hc = fmaf(Pt, Hc, Ht);
      Pc = Pc * Pt;
    }
    PcT[ntl] = Pc; HcT[ntl] = Hc;
  }

  // ---- publish this wave's 32-state pair aggregate immediately ----
  if (g == 0) {
#pragma unroll
    for (int ntl = 0; ntl < 2; ++ntl) {
      unsigned long long v = ((unsigned long long)__float_as_uint(HcT[ntl]) << 32) |
                             (unsigned long long)__float_as_uint(PcT[ntl]);
      part_store(&partA[bc * 128 + 32 * w + 16 * ntl + c], v);
    }
  }

  // ---- C GEMM (independent; overlaps other blocks' publishes) ----
  floatx4 Cc[2][8];
#pragma unroll
  for (int ntl = 0; ntl < 2; ++ntl)
#pragma unroll
    for (int mt = 0; mt < 8; ++mt) Cc[ntl][mt] = (floatx4){0.f, 0.f, 0.f, 0.f};
#pragma unroll
  for (int kk = 0; kk < 4; ++kk) {
    bf16x8 fC0 = WFRAG(2, 2 * w + 0, kk);
    bf16x8 fC1 = WFRAG(2, 2 * w + 1, kk);
#pragma unroll
    for (int mt = 0; mt < 8; ++mt) {
      bf16x8 a = *(const bf16x8*)&xb[(16 * mt + c) * XSTR + 8 * g + 32 * kk];
      Cc[0][mt] = __builtin_amdgcn_mfma_f32_16x16x32_bf16(a, fC0, Cc[0][mt], 0, 0, 0);
      Cc[1][mt] = __builtin_amdgcn_mfma_f32_16x16x32_bf16(a, fC1, Cc[1][mt], 0, 0, 0);
    }
  }

  // ---- decoupled lookback with inclusive shortcut (lanes 0..31 of each wave) ----
  float h0v[2];
  float P0f = 1.0f, H0f = 0.0f;        // full-prefix (P,H) on walker lanes
  {
    const int s = 32 * w + (lane & 31);
    if (lane < 32) {
      float RP = 1.0f, RH = 0.0f;
      int j = cpair - 1;
      while (j >= 0) {
        // probe the inclusive record at j: if ready, it closes the whole prefix
        unsigned long long vi = part_load(&partI[((j << 3) | b) * 128 + s]);
        if ((unsigned)vi != 0u) {
          float Pi = __uint_as_float((unsigned)vi);
          float Hi = __uint_as_float((unsigned)(vi >> 32));
          RH = fmaf(RP, Hi, RH);
          RP = RP * Pi;
          break;
        }
        int nb = (j >= 7) ? 8 : (j + 1);
        unsigned long long v[8];
#pragma unroll
        for (int q = 0; q < 8; ++q)
          if (q < nb) v[q] = part_load(&partA[(((j - q) << 3) | b) * 128 + s]);
#pragma unroll
        for (int q = 0; q < 8; ++q) {
          if (q < nb) {
            unsigned long long vv = v[q];
            const unsigned long long* ap = &partA[(((j - q) << 3) | b) * 128 + s];
            while ((unsigned)vv == 0u) {     // P>0 always => low word != 0 when ready
              __builtin_amdgcn_s_sleep(2);
              vv = part_load(ap);
            }
            float Pj = __uint_as_float((unsigned)vv);
            float Hj = __uint_as_float((unsigned)(vv >> 32));
            RH = fmaf(RP, Hj, RH);
            RP = RP * Pj;
          }
        }
        j -= nb;
      }
      P0f = RP; H0f = RH;
    }
#pragma unroll
    for (int ntl = 0; ntl < 2; ++ntl)
      h0v[ntl] = __shfl(H0f, 16 * ntl + c);
  }

  // ---- publish inclusive prefix (walker lanes; flag word clamped nonzero) ----
  if (lane < 32) {
    float Pct = (lane & 16) ? PcT[1] : PcT[0];
    float Hct = (lane & 16) ? HcT[1] : HcT[0];
    float Pinc = fmaxf(Pct * P0f, 1.2e-38f);
    float Hinc = fmaf(Pct, H0f, Hct);
    unsigned long long vI = ((unsigned long long)__float_as_uint(Hinc) << 32) |
                            (unsigned long long)__float_as_uint(Pinc);
    part_store(&partI[bc * 128 + 32 * w + lane], vI);
  }

  __syncthreads();   // all xb (x) reads done in every wave; safe to reuse as hT

  // ---- fixup h = h_local + cumP*h0, y partials, hT ----
#pragma unroll
  for (int mt = 0; mt < 8; ++mt) {
    float yv[4] = {0.f, 0.f, 0.f, 0.f};
#pragma unroll
    for (int ntl = 0; ntl < 2; ++ntl)
#pragma unroll
      for (int i = 0; i < 4; ++i) {
        float hv = fmaf(A_[ntl][mt][i], h0v[ntl], U_[ntl][mt][i]);
        yv[i] = fmaf(Cc[ntl][mt][i], hv, yv[i]);
        xb[(16 * mt + 4 * g + i) * XSTR + 32 * w + 16 * ntl + c] = f2bf(hv);
      }
    // reduce y over the 16 states per c-group; this wave's partial into yxa
#pragma unroll
    for (int i = 0; i < 4; ++i) {
      float y = yv[i];
      y += __shfl_xor(y, 1);
      y += __shfl_xor(y, 2);
      y += __shfl_xor(y, 4);
      y += __shfl_xor(y, 8);
      if (c == 0) yxa[w * PAIRROWS + 16 * mt + 4 * g + i] = y;
    }
  }

  __syncthreads();
  if (tid < PAIRROWS) {   // y_total * x0 per row (x0s reused)
    float y = yxa[tid] + yxa[PAIRROWS + tid] + yxa[2 * PAIRROWS + tid] + yxa[3 * PAIRROWS + tid];
    x0s[tid] = y * x0s[tid];
  }
  __syncthreads();

  // ---- out GEMM: A = h bf16 [t][s], B = Wout (this wave's 2 d-slices) ----
  floatx4 Oc[2][8];
#pragma unroll
  for (int ntl = 0; ntl < 2; ++ntl)
#pragma unroll
    for (int mt = 0; mt < 8; ++mt) Oc[ntl][mt] = (floatx4){0.f, 0.f, 0.f, 0.f};
#pragma unroll
  for (int kk = 0; kk < 4; ++kk) {
    bf16x8 fO0 = WFRAG(3, 2 * w + 0, kk);
    bf16x8 fO1 = WFRAG(3, 2 * w + 1, kk);
#pragma unroll
    for (int mt = 0; mt < 8; ++mt) {
      bf16x8 h = *(const bf16x8*)&xb[(16 * mt + c) * XSTR + 8 * g + 32 * kk];
      Oc[0][mt] = __builtin_amdgcn_mfma_f32_16x16x32_bf16(h, fO0, Oc[0][mt], 0, 0, 0);
      Oc[1][mt] = __builtin_amdgcn_mfma_f32_16x16x32_bf16(h, fO1, Oc[1][mt], 0, 0, 0);
    }
  }

#pragma unroll
  for (int mt = 0; mt < 8; ++mt)
#pragma unroll
    for (int i = 0; i < 4; ++i) {
      int row = 16 * mt + 4 * g + i;
      float yt = x0s[row];
#pragma unroll
      for (int ntl = 0; ntl < 2; ++ntl)
        out[(chunk_t0 + row) * D_ + 32 * w + 16 * ntl + c] = Oc[ntl][mt][i] + yt;
    }
}

extern "C" void kernel_launch(void* const* d_in, const int* in_sizes, int n_in,
                              void* d_out, int out_size, void* d_ws, size_t ws_size,
                              hipStream_t stream) {
  const float* x    = (const float*)d_in[0];
  const float* logA = (const float*)d_in[1];
  const float* W_B  = (const float*)d_in[2];
  const float* W_C  = (const float*)d_in[3];
  const float* W_dt = (const float*)d_in[4];
  const float* b_dt = (const float*)d_in[5];
  const float* W_out= (const float*)d_in[6];
  float* out = (float*)d_out;
  float* ws  = (float*)d_ws;

  k0_prep<<<64, 256, 0, stream>>>(W_dt, W_B, W_C, W_out, logA, ws);
  k_main<<<NBLK, 256, 0, stream>>>(x, b_dt, out, ws);
}

// Round 6
// 127.366 us; speedup vs baseline: 1.0011x; 1.0011x over previous
//
#include <hip/hip_runtime.h>
#include <hip/hip_bf16.h>

// Problem constants
#define B_ 8
#define T_ 8192
#define D_ 128
#define S_ 128
#define CK 64
#define NC 128           // T_/CK
#define NCHUNK (B_*NC)   // 1024
#define XSTR 140         // xb row stride in halfwords (280B; measured 0 bank conflicts)

typedef __attribute__((ext_vector_type(8))) __bf16 bf16x8;
typedef __attribute__((ext_vector_type(4))) float floatx4;

// ws layout (floats)
#define WS_WBF     0                        // 4 mats bf16 (frag-swizzled) = 32768 floats
#define WS_AVEC    32768                    // 128
#define WS_PART    32896                    // u64[NCHUNK*128] chunk aggregates (P,H)
#define WS_PARTI   (32896 + 262144)         // u64[NCHUNK*128] inclusive prefixes

__device__ __forceinline__ unsigned short f2bf(float f) {
  __hip_bfloat16 b = __float2bfloat16(f);
  return *(unsigned short*)&b;
}

__device__ __forceinline__ float softplus1(float z) {
  float sp = fmaxf(z, 0.0f) + __logf(1.0f + __expf(-fabsf(z)));
  return fminf(sp, 1.0f);
}

__device__ __forceinline__ unsigned long long part_load(const unsigned long long* p) {
  return __hip_atomic_load(p, __ATOMIC_RELAXED, __HIP_MEMORY_SCOPE_AGENT);
}
__device__ __forceinline__ void part_store(unsigned long long* p, unsigned long long v) {
  __hip_atomic_store(p, v, __ATOMIC_RELAXED, __HIP_MEMORY_SCOPE_AGENT);
}

// Ready test without zero-init: a published P is a positive normal float
// (P >= e^-32). Harness poison is 0xAA bytes -> low word 0xAAAAAAAA has the
// sign bit set (negative) -> not ready. 0 -> not ready. No zeroing needed.
__device__ __forceinline__ bool part_ready(unsigned long long v) {
  return (int)(unsigned)v > 0;
}

// ---------------- K0: weights -> bf16 fragment order (repack only) ----------------
// wb[(((m*8+nt)*4+kk)*64 + lane)*8 + e] <- W_m[16nt + (lane&15)][32kk + 8*(lane>>4) + e]
__global__ __launch_bounds__(256) void k0_prep(
    const float* __restrict__ Wdt, const float* __restrict__ WB,
    const float* __restrict__ WC,  const float* __restrict__ Wout,
    const float* __restrict__ logA, float* __restrict__ ws) {
  unsigned short* wb = (unsigned short*)(ws + WS_WBF);
  const float* srcs[4] = {Wdt, WB, WC, Wout};
  int fid = blockIdx.x * 256 + threadIdx.x;   // 0..8191, one fragment per thread
  {
    int lane = fid & 63;
    int kk   = (fid >> 6) & 3;
    int nt   = (fid >> 8) & 7;
    int m    = fid >> 11;
    int c = lane & 15, g = lane >> 4;
    const float* src = srcs[m] + (16 * nt + c) * 128 + 32 * kk + 8 * g;
    float4 v0 = *(const float4*)src;
    float4 v1 = *(const float4*)(src + 4);
    unsigned short o[8];
    o[0] = f2bf(v0.x); o[1] = f2bf(v0.y); o[2] = f2bf(v0.z); o[3] = f2bf(v0.w);
    o[4] = f2bf(v1.x); o[5] = f2bf(v1.y); o[6] = f2bf(v1.z); o[7] = f2bf(v1.w);
    *(ushort4*)&wb[fid * 8]     = *(ushort4*)&o[0];
    *(ushort4*)&wb[fid * 8 + 4] = *(ushort4*)&o[4];
  }
  if (blockIdx.x == 0 && threadIdx.x < 128)
    ws[WS_AVEC + threadIdx.x] = -fminf(expf(logA[threadIdx.x]), 10.0f);
}

// fragment load: contiguous 1KB per wave
#define WFRAG(mat, nt, kk) \
  (*(const bf16x8*)&wb[(((((mat) * 8 + (nt)) * 4) + (kk)) * 64 + lane) * 8])

// ---------------- K_MAIN ----------------
// N-split wave ownership: wave w owns states 32w..32w+31 (nt tiles 2w, 2w+1) for
// ALL 64 rows of the chunk (m-tiles mt=0..3). Weights read once per block per
// GEMM; scan + carry publish + lookback are wave-local. Decoupled lookback with
// inclusive-prefix shortcut. Tail latency shaved: Wout fragments prefetched
// before the lookback (hidden under spin+fixup); y-finalize folded into the
// out-GEMM epilogue (one fewer barrier, no serial tid<64 phase).
__global__ __launch_bounds__(256, 3) void k_main(
    const float* __restrict__ x, const float* __restrict__ bdt,
    float* __restrict__ out, float* __restrict__ ws) {
  __shared__ __align__(16) unsigned short xb[64 * XSTR];  // x bf16, reused as hT
  __shared__ float x0s[64];                               // x[t,0] fp32 (read-only)
  __shared__ float yxa[4 * 64];                           // per-wave y partials

  const int tid  = threadIdx.x;
  const int bc   = blockIdx.x;
  const int b    = bc & 7;
  const int cidx = bc >> 3;
  const long chunk_t0 = (long)b * T_ + (long)cidx * CK;
  const int w    = tid >> 6;
  const int lane = tid & 63;
  const int g    = lane >> 4;
  const int c    = lane & 15;

  float Av2[2], Bd2[2];
#pragma unroll
  for (int ntl = 0; ntl < 2; ++ntl) {
    int s = 32 * w + 16 * ntl + c;
    Av2[ntl] = ws[WS_AVEC + s];
    Bd2[ntl] = bdt[s];
  }

  // ---- stage x -> bf16 LDS (+ x0 fp32) ----
  const float4* x4 = (const float4*)(x + chunk_t0 * D_);
#pragma unroll
  for (int i = 0; i < 8; ++i) {
    int f4 = tid + 256 * i;
    int t  = f4 >> 5;
    int d0 = (f4 & 31) << 2;
    float4 v = x4[f4];
    ushort4 o;
    o.x = f2bf(v.x); o.y = f2bf(v.y); o.z = f2bf(v.z); o.w = f2bf(v.w);
    *(ushort4*)&xb[t * XSTR + d0] = o;
  }
  if (tid < 64) x0s[tid] = x[(chunk_t0 + tid) * D_];
  __syncthreads();

  const unsigned short* wb = (const unsigned short*)(ws + WS_WBF);
  unsigned long long* partA = (unsigned long long*)(ws + WS_PART);
  unsigned long long* partI = (unsigned long long*)(ws + WS_PARTI);

  // ---- dt & B GEMMs: A = x rows (4 m-tiles), B = this wave's 2 nt slices ----
  floatx4 A_[2][4], U_[2][4];
#pragma unroll
  for (int ntl = 0; ntl < 2; ++ntl)
#pragma unroll
    for (int mt = 0; mt < 4; ++mt) {
      A_[ntl][mt] = (floatx4){0.f, 0.f, 0.f, 0.f};
      U_[ntl][mt] = (floatx4){0.f, 0.f, 0.f, 0.f};
    }
#pragma unroll
  for (int kk = 0; kk < 4; ++kk) {
    bf16x8 fD0 = WFRAG(0, 2 * w + 0, kk);
    bf16x8 fD1 = WFRAG(0, 2 * w + 1, kk);
    bf16x8 fB0 = WFRAG(1, 2 * w + 0, kk);
    bf16x8 fB1 = WFRAG(1, 2 * w + 1, kk);
#pragma unroll
    for (int mt = 0; mt < 4; ++mt) {
      bf16x8 a = *(const bf16x8*)&xb[(16 * mt + c) * XSTR + 8 * g + 32 * kk];
      A_[0][mt] = __builtin_amdgcn_mfma_f32_16x16x32_bf16(a, fD0, A_[0][mt], 0, 0, 0);
      A_[1][mt] = __builtin_amdgcn_mfma_f32_16x16x32_bf16(a, fD1, A_[1][mt], 0, 0, 0);
      U_[0][mt] = __builtin_amdgcn_mfma_f32_16x16x32_bf16(a, fB0, U_[0][mt], 0, 0, 0);
      U_[1][mt] = __builtin_amdgcn_mfma_f32_16x16x32_bf16(a, fB1, U_[1][mt], 0, 0, 0);
    }
  }

  // ---- elementwise -> a (A_), u (U_) ----
#pragma unroll
  for (int ntl = 0; ntl < 2; ++ntl)
#pragma unroll
    for (int mt = 0; mt < 4; ++mt)
#pragma unroll
      for (int i = 0; i < 4; ++i) {
        float dt = softplus1(A_[ntl][mt][i] + Bd2[ntl]);
        float u  = U_[ntl][mt][i] * dt;
        float la = fmaxf(fminf(dt * Av2[ntl], 0.0f), -0.5f);
        A_[ntl][mt][i] = __expf(la);
        U_[ntl][mt][i] = u;
      }

  // ---- wave-local scan over all 64 rows (4 m-tiles chained in-register) ----
  float PcT[2], HcT[2];
#pragma unroll
  for (int ntl = 0; ntl < 2; ++ntl) {
    float Pc = 1.0f, Hc = 0.0f;   // carry entering current m-tile (from chunk start)
#pragma unroll
    for (int mt = 0; mt < 4; ++mt) {
      // intra-lane inclusive over the lane's 4 rows
      float P = A_[ntl][mt][0], H = U_[ntl][mt][0];
#pragma unroll
      for (int i = 1; i < 4; ++i) {
        H = fmaf(H, A_[ntl][mt][i], U_[ntl][mt][i]);
        P = P * A_[ntl][mt][i];
        A_[ntl][mt][i] = P;
        U_[ntl][mt][i] = H;
      }
      // Kogge-Stone over g-segments (16-row tile)
      float Po = __shfl(P, (lane - 16) & 63), Ho = __shfl(H, (lane - 16) & 63);
      if (g >= 1) { H = fmaf(Ho, P, H); P = Po * P; }
      Po = __shfl(P, (lane - 32) & 63); Ho = __shfl(H, (lane - 32) & 63);
      if (g >= 2) { H = fmaf(Ho, P, H); P = Po * P; }
      // tile totals (inclusive over 16 rows) live at g==3
      float Pt = __shfl(P, 48 + c);
      float Ht = __shfl(H, 48 + c);
      // exclusive entering this lane's segment (within tile)
      float Pe = __shfl(P, (lane - 16) & 63), He = __shfl(H, (lane - 16) & 63);
      if (g == 0) { Pe = 1.0f; He = 0.0f; }
      // compose with chunk carry entering this tile
      float Hent = fmaf(Pe, Hc, He);
      float Pent = Pe * Pc;
#pragma unroll
      for (int i = 0; i < 4; ++i) {
        U_[ntl][mt][i] = fmaf(A_[ntl][mt][i], Hent, U_[ntl][mt][i]);  // h_local
        A_[ntl][mt][i] = A_[ntl][mt][i] * Pent;                       // cumP
      }
      Hc = fmaf(Pt, Hc, Ht);
      Pc = Pc * Pt;
    }
    PcT[ntl] = Pc; HcT[ntl] = Hc;
  }

  // ---- publish this wave's 32-state aggregate immediately ----
  if (g == 0) {
#pragma unroll
    for (int ntl = 0; ntl < 2; ++ntl) {
      unsigned long long v = ((unsigned long long)__float_as_uint(HcT[ntl]) << 32) |
                             (unsigned long long)__float_as_uint(PcT[ntl]);
      part_store(&partA[bc * 128 + 32 * w + 16 * ntl + c], v);
    }
  }

  // ---- C GEMM (independent; overlaps other blocks' publishes) ----
  floatx4 Cc[2][4];
#pragma unroll
  for (int ntl = 0; ntl < 2; ++ntl)
#pragma unroll
    for (int mt = 0; mt < 4; ++mt) Cc[ntl][mt] = (floatx4){0.f, 0.f, 0.f, 0.f};
#pragma unroll
  for (int kk = 0; kk < 4; ++kk) {
    bf16x8 fC0 = WFRAG(2, 2 * w + 0, kk);
    bf16x8 fC1 = WFRAG(2, 2 * w + 1, kk);
#pragma unroll
    for (int mt = 0; mt < 4; ++mt) {
      bf16x8 a = *(const bf16x8*)&xb[(16 * mt + c) * XSTR + 8 * g + 32 * kk];
      Cc[0][mt] = __builtin_amdgcn_mfma_f32_16x16x32_bf16(a, fC0, Cc[0][mt], 0, 0, 0);
      Cc[1][mt] = __builtin_amdgcn_mfma_f32_16x16x32_bf16(a, fC1, Cc[1][mt], 0, 0, 0);
    }
  }

  // ---- prefetch Wout fragments (independent of lookback; hides their L2
  //      latency under the spin-wait + fixup instead of the serial tail) ----
  bf16x8 fO0[4], fO1[4];
#pragma unroll
  for (int kk = 0; kk < 4; ++kk) {
    fO0[kk] = WFRAG(3, 2 * w + 0, kk);
    fO1[kk] = WFRAG(3, 2 * w + 1, kk);
  }

  // ---- decoupled lookback with inclusive shortcut (lanes 0..31 of each wave) ----
  float h0v[2];
  float P0f = 1.0f, H0f = 0.0f;        // full-prefix (P,H) on walker lanes
  {
    const int s = 32 * w + (lane & 31);
    if (lane < 32) {
      float RP = 1.0f, RH = 0.0f;
      int j = cidx - 1;
      while (j >= 0) {
        // probe the inclusive record at j: if ready, it closes the whole prefix
        unsigned long long vi = part_load(&partI[((j << 3) | b) * 128 + s]);
        if (part_ready(vi)) {
          float Pi = __uint_as_float((unsigned)vi);
          float Hi = __uint_as_float((unsigned)(vi >> 32));
          RH = fmaf(RP, Hi, RH);
          RP = RP * Pi;
          break;
        }
        int nb = (j >= 7) ? 8 : (j + 1);
        unsigned long long v[8];
#pragma unroll
        for (int q = 0; q < 8; ++q)
          if (q < nb) v[q] = part_load(&partA[(((j - q) << 3) | b) * 128 + s]);
#pragma unroll
        for (int q = 0; q < 8; ++q) {
          if (q < nb) {
            unsigned long long vv = v[q];
            const unsigned long long* ap = &partA[(((j - q) << 3) | b) * 128 + s];
            while (!part_ready(vv)) {
              __builtin_amdgcn_s_sleep(2);
              vv = part_load(ap);
            }
            float Pj = __uint_as_float((unsigned)vv);
            float Hj = __uint_as_float((unsigned)(vv >> 32));
            RH = fmaf(RP, Hj, RH);
            RP = RP * Pj;
          }
        }
        j -= nb;
      }
      P0f = RP; H0f = RH;
    }
#pragma unroll
    for (int ntl = 0; ntl < 2; ++ntl)
      h0v[ntl] = __shfl(H0f, 16 * ntl + c);
  }

  // ---- publish inclusive prefix (walker lanes; P clamped to positive normal) ----
  if (lane < 32) {
    float Pct = (lane & 16) ? PcT[1] : PcT[0];
    float Hct = (lane & 16) ? HcT[1] : HcT[0];
    float Pinc = fmaxf(Pct * P0f, 1.2e-38f);
    float Hinc = fmaf(Pct, H0f, Hct);
    unsigned long long vI = ((unsigned long long)__float_as_uint(Hinc) << 32) |
                            (unsigned long long)__float_as_uint(Pinc);
    part_store(&partI[bc * 128 + 32 * w + lane], vI);
  }

  __syncthreads();   // all xb (x) reads done in every wave; safe to reuse as hT

  // ---- fixup h = h_local + cumP*h0, y partials, hT ----
#pragma unroll
  for (int mt = 0; mt < 4; ++mt) {
    float yv[4] = {0.f, 0.f, 0.f, 0.f};
#pragma unroll
    for (int ntl = 0; ntl < 2; ++ntl)
#pragma unroll
      for (int i = 0; i < 4; ++i) {
        float hv = fmaf(A_[ntl][mt][i], h0v[ntl], U_[ntl][mt][i]);
        yv[i] = fmaf(Cc[ntl][mt][i], hv, yv[i]);
        xb[(16 * mt + 4 * g + i) * XSTR + 32 * w + 16 * ntl + c] = f2bf(hv);
      }
    // reduce y over the 16 states per c-group; this wave's partial into yxa
#pragma unroll
    for (int i = 0; i < 4; ++i) {
      float y = yv[i];
      y += __shfl_xor(y, 1);
      y += __shfl_xor(y, 2);
      y += __shfl_xor(y, 4);
      y += __shfl_xor(y, 8);
      if (c == 0) yxa[w * 64 + 16 * mt + 4 * g + i] = y;
    }
  }

  __syncthreads();   // hT + yxa ready

  // ---- out GEMM: A = h bf16 [t][s], B = Wout (this wave's 2 d-slices) ----
  floatx4 Oc[2][4];
#pragma unroll
  for (int ntl = 0; ntl < 2; ++ntl)
#pragma unroll
    for (int mt = 0; mt < 4; ++mt) Oc[ntl][mt] = (floatx4){0.f, 0.f, 0.f, 0.f};
#pragma unroll
  for (int kk = 0; kk < 4; ++kk) {
#pragma unroll
    for (int mt = 0; mt < 4; ++mt) {
      bf16x8 h = *(const bf16x8*)&xb[(16 * mt + c) * XSTR + 8 * g + 32 * kk];
      Oc[0][mt] = __builtin_amdgcn_mfma_f32_16x16x32_bf16(h, fO0[kk], Oc[0][mt], 0, 0, 0);
      Oc[1][mt] = __builtin_amdgcn_mfma_f32_16x16x32_bf16(h, fO1[kk], Oc[1][mt], 0, 0, 0);
    }
  }

  // ---- epilogue: y folded here (no extra barrier / serial phase) ----
#pragma unroll
  for (int mt = 0; mt < 4; ++mt)
#pragma unroll
    for (int i = 0; i < 4; ++i) {
      int row = 16 * mt + 4 * g + i;
      float yt = (yxa[row] + yxa[64 + row] + yxa[128 + row] + yxa[192 + row]) * x0s[row];
#pragma unroll
      for (int ntl = 0; ntl < 2; ++ntl)
        out[(chunk_t0 + row) * D_ + 32 * w + 16 * ntl + c] = Oc[ntl][mt][i] + yt;
    }
}

extern "C" void kernel_launch(void* const* d_in, const int* in_sizes, int n_in,
                              void* d_out, int out_size, void* d_ws, size_t ws_size,
                              hipStream_t stream) {
  const float* x    = (const float*)d_in[0];
  const float* logA = (const float*)d_in[1];
  const float* W_B  = (const float*)d_in[2];
  const float* W_C  = (const float*)d_in[3];
  const float* W_dt = (const float*)d_in[4];
  const float* b_dt = (const float*)d_in[5];
  const float* W_out= (const float*)d_in[6];
  float* out = (float*)d_out;
  float* ws  = (float*)d_ws;

  k0_prep<<<32, 256, 0, stream>>>(W_dt, W_B, W_C, W_out, logA, ws);
  k_main<<<NCHUNK, 256, 0, stream>>>(x, b_dt, out, ws);
}

// Round 7
// 116.494 us; speedup vs baseline: 1.0945x; 1.0933x over previous
//
#include <hip/hip_runtime.h>
#include <hip/hip_bf16.h>

// Problem constants
#define B_ 8
#define T_ 8192
#define D_ 128
#define S_ 128
#define CK 64
#define NC 128           // T_/CK
#define NCHUNK (B_*NC)   // 1024
#define XSTR 140         // xb row stride in halfwords (280B; measured 0 bank conflicts)

typedef __attribute__((ext_vector_type(8))) __bf16 bf16x8;
typedef __attribute__((ext_vector_type(4))) float floatx4;

// ws layout (floats)
#define WS_WBF     0                        // 4 mats bf16 (frag-swizzled) = 32768 floats
#define WS_AVEC    32768                    // 128
#define WS_PART    32896                    // u64[NCHUNK*128] chunk aggregates (P,H)
#define WS_PARTI   (32896 + 262144)         // u64[NCHUNK*128] inclusive prefixes

__device__ __forceinline__ unsigned short f2bf(float f) {
  __hip_bfloat16 b = __float2bfloat16(f);
  return *(unsigned short*)&b;
}

__device__ __forceinline__ float softplus1(float z) {
  float sp = fmaxf(z, 0.0f) + __logf(1.0f + __expf(-fabsf(z)));
  return fminf(sp, 1.0f);
}

__device__ __forceinline__ unsigned long long part_load(const unsigned long long* p) {
  return __hip_atomic_load(p, __ATOMIC_RELAXED, __HIP_MEMORY_SCOPE_AGENT);
}
__device__ __forceinline__ void part_store(unsigned long long* p, unsigned long long v) {
  __hip_atomic_store(p, v, __ATOMIC_RELAXED, __HIP_MEMORY_SCOPE_AGENT);
}

// ---------------- K0: weights -> bf16 fragment order; zero partials ----------------
// Zeroing the partials ALSO pulls that region into L2 right before k_main,
// making the lookback probes L2-hits instead of HBM round-trips (round-6 lesson).
// wb[(((m*8+nt)*4+kk)*64 + lane)*8 + e] <- W_m[16nt + (lane&15)][32kk + 8*(lane>>4) + e]
__global__ __launch_bounds__(256) void k0_prep(
    const float* __restrict__ Wdt, const float* __restrict__ WB,
    const float* __restrict__ WC,  const float* __restrict__ Wout,
    const float* __restrict__ logA, float* __restrict__ ws) {
  unsigned short* wb = (unsigned short*)(ws + WS_WBF);
  const float* srcs[4] = {Wdt, WB, WC, Wout};
  int gid = blockIdx.x * 256 + threadIdx.x;   // 0..16383
  if (gid < 8192) {
    int fid = gid;                            // one fragment per thread
    int lane = fid & 63;
    int kk   = (fid >> 6) & 3;
    int nt   = (fid >> 8) & 7;
    int m    = fid >> 11;
    int c = lane & 15, g = lane >> 4;
    const float* src = srcs[m] + (16 * nt + c) * 128 + 32 * kk + 8 * g;
    float4 v0 = *(const float4*)src;
    float4 v1 = *(const float4*)(src + 4);
    unsigned short o[8];
    o[0] = f2bf(v0.x); o[1] = f2bf(v0.y); o[2] = f2bf(v0.z); o[3] = f2bf(v0.w);
    o[4] = f2bf(v1.x); o[5] = f2bf(v1.y); o[6] = f2bf(v1.z); o[7] = f2bf(v1.w);
    *(ushort4*)&wb[fid * 8]     = *(ushort4*)&o[0];
    *(ushort4*)&wb[fid * 8 + 4] = *(ushort4*)&o[4];
  }
  // zero BOTH partials arrays (2 MB; ws is poisoned 0xAA before every call)
  unsigned long long* part = (unsigned long long*)(ws + WS_PART);
#pragma unroll
  for (int i = 0; i < 16; ++i)
    part[gid + 16384 * i] = 0ull;
  if (blockIdx.x == 0 && threadIdx.x < 128)
    ws[WS_AVEC + threadIdx.x] = -fminf(expf(logA[threadIdx.x]), 10.0f);
}

// fragment load: contiguous 1KB per wave
#define WFRAG(mat, nt, kk) \
  (*(const bf16x8*)&wb[(((((mat) * 8 + (nt)) * 4) + (kk)) * 64 + lane) * 8])

// ---------------- K_MAIN ----------------
// N-split wave ownership: wave w owns states 32w..32w+31 (nt tiles 2w, 2w+1) for
// ALL 64 rows of the chunk (m-tiles mt=0..3). Weights read once per block per
// GEMM; scan + carry publish + lookback are wave-local. Decoupled lookback with
// inclusive-prefix shortcut. y*x0 finalize folded into the out-GEMM epilogue
// (one fewer barrier, no serial tid<64 phase). NO register state is carried
// across the lookback loop (round-6 lesson: it spills to scratch).
__global__ __launch_bounds__(256, 3) void k_main(
    const float* __restrict__ x, const float* __restrict__ bdt,
    float* __restrict__ out, float* __restrict__ ws) {
  __shared__ __align__(16) unsigned short xb[64 * XSTR];  // x bf16, reused as hT
  __shared__ float x0s[64];                               // x[t,0] fp32 (read-only)
  __shared__ float yxa[4 * 64];                           // per-wave y partials

  const int tid  = threadIdx.x;
  const int bc   = blockIdx.x;
  const int b    = bc & 7;
  const int cidx = bc >> 3;
  const long chunk_t0 = (long)b * T_ + (long)cidx * CK;
  const int w    = tid >> 6;
  const int lane = tid & 63;
  const int g    = lane >> 4;
  const int c    = lane & 15;

  float Av2[2], Bd2[2];
#pragma unroll
  for (int ntl = 0; ntl < 2; ++ntl) {
    int s = 32 * w + 16 * ntl + c;
    Av2[ntl] = ws[WS_AVEC + s];
    Bd2[ntl] = bdt[s];
  }

  // ---- stage x -> bf16 LDS (+ x0 fp32) ----
  const float4* x4 = (const float4*)(x + chunk_t0 * D_);
#pragma unroll
  for (int i = 0; i < 8; ++i) {
    int f4 = tid + 256 * i;
    int t  = f4 >> 5;
    int d0 = (f4 & 31) << 2;
    float4 v = x4[f4];
    ushort4 o;
    o.x = f2bf(v.x); o.y = f2bf(v.y); o.z = f2bf(v.z); o.w = f2bf(v.w);
    *(ushort4*)&xb[t * XSTR + d0] = o;
  }
  if (tid < 64) x0s[tid] = x[(chunk_t0 + tid) * D_];
  __syncthreads();

  const unsigned short* wb = (const unsigned short*)(ws + WS_WBF);
  unsigned long long* partA = (unsigned long long*)(ws + WS_PART);
  unsigned long long* partI = (unsigned long long*)(ws + WS_PARTI);

  // ---- dt & B GEMMs: A = x rows (4 m-tiles), B = this wave's 2 nt slices ----
  floatx4 A_[2][4], U_[2][4];
#pragma unroll
  for (int ntl = 0; ntl < 2; ++ntl)
#pragma unroll
    for (int mt = 0; mt < 4; ++mt) {
      A_[ntl][mt] = (floatx4){0.f, 0.f, 0.f, 0.f};
      U_[ntl][mt] = (floatx4){0.f, 0.f, 0.f, 0.f};
    }
#pragma unroll
  for (int kk = 0; kk < 4; ++kk) {
    bf16x8 fD0 = WFRAG(0, 2 * w + 0, kk);
    bf16x8 fD1 = WFRAG(0, 2 * w + 1, kk);
    bf16x8 fB0 = WFRAG(1, 2 * w + 0, kk);
    bf16x8 fB1 = WFRAG(1, 2 * w + 1, kk);
#pragma unroll
    for (int mt = 0; mt < 4; ++mt) {
      bf16x8 a = *(const bf16x8*)&xb[(16 * mt + c) * XSTR + 8 * g + 32 * kk];
      A_[0][mt] = __builtin_amdgcn_mfma_f32_16x16x32_bf16(a, fD0, A_[0][mt], 0, 0, 0);
      A_[1][mt] = __builtin_amdgcn_mfma_f32_16x16x32_bf16(a, fD1, A_[1][mt], 0, 0, 0);
      U_[0][mt] = __builtin_amdgcn_mfma_f32_16x16x32_bf16(a, fB0, U_[0][mt], 0, 0, 0);
      U_[1][mt] = __builtin_amdgcn_mfma_f32_16x16x32_bf16(a, fB1, U_[1][mt], 0, 0, 0);
    }
  }

  // ---- elementwise -> a (A_), u (U_) ----
#pragma unroll
  for (int ntl = 0; ntl < 2; ++ntl)
#pragma unroll
    for (int mt = 0; mt < 4; ++mt)
#pragma unroll
      for (int i = 0; i < 4; ++i) {
        float dt = softplus1(A_[ntl][mt][i] + Bd2[ntl]);
        float u  = U_[ntl][mt][i] * dt;
        float la = fmaxf(fminf(dt * Av2[ntl], 0.0f), -0.5f);
        A_[ntl][mt][i] = __expf(la);
        U_[ntl][mt][i] = u;
      }

  // ---- wave-local scan over all 64 rows (4 m-tiles chained in-register) ----
  float PcT[2], HcT[2];
#pragma unroll
  for (int ntl = 0; ntl < 2; ++ntl) {
    float Pc = 1.0f, Hc = 0.0f;   // carry entering current m-tile (from chunk start)
#pragma unroll
    for (int mt = 0; mt < 4; ++mt) {
      // intra-lane inclusive over the lane's 4 rows
      float P = A_[ntl][mt][0], H = U_[ntl][mt][0];
#pragma unroll
      for (int i = 1; i < 4; ++i) {
        H = fmaf(H, A_[ntl][mt][i], U_[ntl][mt][i]);
        P = P * A_[ntl][mt][i];
        A_[ntl][mt][i] = P;
        U_[ntl][mt][i] = H;
      }
      // Kogge-Stone over g-segments (16-row tile)
      float Po = __shfl(P, (lane - 16) & 63), Ho = __shfl(H, (lane - 16) & 63);
      if (g >= 1) { H = fmaf(Ho, P, H); P = Po * P; }
      Po = __shfl(P, (lane - 32) & 63); Ho = __shfl(H, (lane - 32) & 63);
      if (g >= 2) { H = fmaf(Ho, P, H); P = Po * P; }
      // tile totals (inclusive over 16 rows) live at g==3
      float Pt = __shfl(P, 48 + c);
      float Ht = __shfl(H, 48 + c);
      // exclusive entering this lane's segment (within tile)
      float Pe = __shfl(P, (lane - 16) & 63), He = __shfl(H, (lane - 16) & 63);
      if (g == 0) { Pe = 1.0f; He = 0.0f; }
      // compose with chunk carry entering this tile
      float Hent = fmaf(Pe, Hc, He);
      float Pent = Pe * Pc;
#pragma unroll
      for (int i = 0; i < 4; ++i) {
        U_[ntl][mt][i] = fmaf(A_[ntl][mt][i], Hent, U_[ntl][mt][i]);  // h_local
        A_[ntl][mt][i] = A_[ntl][mt][i] * Pent;                       // cumP
      }
      Hc = fmaf(Pt, Hc, Ht);
      Pc = Pc * Pt;
    }
    PcT[ntl] = Pc; HcT[ntl] = Hc;
  }

  // ---- publish this wave's 32-state aggregate immediately ----
  if (g == 0) {
#pragma unroll
    for (int ntl = 0; ntl < 2; ++ntl) {
      unsigned long long v = ((unsigned long long)__float_as_uint(HcT[ntl]) << 32) |
                             (unsigned long long)__float_as_uint(PcT[ntl]);
      part_store(&partA[bc * 128 + 32 * w + 16 * ntl + c], v);
    }
  }

  // ---- C GEMM (independent; overlaps other blocks' publishes) ----
  floatx4 Cc[2][4];
#pragma unroll
  for (int ntl = 0; ntl < 2; ++ntl)
#pragma unroll
    for (int mt = 0; mt < 4; ++mt) Cc[ntl][mt] = (floatx4){0.f, 0.f, 0.f, 0.f};
#pragma unroll
  for (int kk = 0; kk < 4; ++kk) {
    bf16x8 fC0 = WFRAG(2, 2 * w + 0, kk);
    bf16x8 fC1 = WFRAG(2, 2 * w + 1, kk);
#pragma unroll
    for (int mt = 0; mt < 4; ++mt) {
      bf16x8 a = *(const bf16x8*)&xb[(16 * mt + c) * XSTR + 8 * g + 32 * kk];
      Cc[0][mt] = __builtin_amdgcn_mfma_f32_16x16x32_bf16(a, fC0, Cc[0][mt], 0, 0, 0);
      Cc[1][mt] = __builtin_amdgcn_mfma_f32_16x16x32_bf16(a, fC1, Cc[1][mt], 0, 0, 0);
    }
  }

  // ---- decoupled lookback with inclusive shortcut (lanes 0..31 of each wave) ----
  float h0v[2];
  float P0f = 1.0f, H0f = 0.0f;        // full-prefix (P,H) on walker lanes
  {
    const int s = 32 * w + (lane & 31);
    if (lane < 32) {
      float RP = 1.0f, RH = 0.0f;
      int j = cidx - 1;
      while (j >= 0) {
        // probe the inclusive record at j: if ready, it closes the whole prefix
        unsigned long long vi = part_load(&partI[((j << 3) | b) * 128 + s]);
        if ((unsigned)vi != 0u) {
          float Pi = __uint_as_float((unsigned)vi);
          float Hi = __uint_as_float((unsigned)(vi >> 32));
          RH = fmaf(RP, Hi, RH);
          RP = RP * Pi;
          break;
        }
        int nb = (j >= 7) ? 8 : (j + 1);
        unsigned long long v[8];
#pragma unroll
        for (int q = 0; q < 8; ++q)
          if (q < nb) v[q] = part_load(&partA[(((j - q) << 3) | b) * 128 + s]);
#pragma unroll
        for (int q = 0; q < 8; ++q) {
          if (q < nb) {
            unsigned long long vv = v[q];
            const unsigned long long* ap = &partA[(((j - q) << 3) | b) * 128 + s];
            while ((unsigned)vv == 0u) {     // P>0 always => low word != 0 when ready
              __builtin_amdgcn_s_sleep(2);
              vv = part_load(ap);
            }
            float Pj = __uint_as_float((unsigned)vv);
            float Hj = __uint_as_float((unsigned)(vv >> 32));
            RH = fmaf(RP, Hj, RH);
            RP = RP * Pj;
          }
        }
        j -= nb;
      }
      P0f = RP; H0f = RH;
    }
#pragma unroll
    for (int ntl = 0; ntl < 2; ++ntl)
      h0v[ntl] = __shfl(H0f, 16 * ntl + c);
  }

  // ---- publish inclusive prefix (walker lanes; flag word clamped nonzero) ----
  if (lane < 32) {
    float Pct = (lane & 16) ? PcT[1] : PcT[0];
    float Hct = (lane & 16) ? HcT[1] : HcT[0];
    float Pinc = fmaxf(Pct * P0f, 1.2e-38f);
    float Hinc = fmaf(Pct, H0f, Hct);
    unsigned long long vI = ((unsigned long long)__float_as_uint(Hinc) << 32) |
                            (unsigned long long)__float_as_uint(Pinc);
    part_store(&partI[bc * 128 + 32 * w + lane], vI);
  }

  __syncthreads();   // all xb (x) reads done in every wave; safe to reuse as hT

  // ---- fixup h = h_local + cumP*h0, y partials, hT ----
#pragma unroll
  for (int mt = 0; mt < 4; ++mt) {
    float yv[4] = {0.f, 0.f, 0.f, 0.f};
#pragma unroll
    for (int ntl = 0; ntl < 2; ++ntl)
#pragma unroll
      for (int i = 0; i < 4; ++i) {
        float hv = fmaf(A_[ntl][mt][i], h0v[ntl], U_[ntl][mt][i]);
        yv[i] = fmaf(Cc[ntl][mt][i], hv, yv[i]);
        xb[(16 * mt + 4 * g + i) * XSTR + 32 * w + 16 * ntl + c] = f2bf(hv);
      }
    // reduce y over the 16 states per c-group; this wave's partial into yxa
#pragma unroll
    for (int i = 0; i < 4; ++i) {
      float y = yv[i];
      y += __shfl_xor(y, 1);
      y += __shfl_xor(y, 2);
      y += __shfl_xor(y, 4);
      y += __shfl_xor(y, 8);
      if (c == 0) yxa[w * 64 + 16 * mt + 4 * g + i] = y;
    }
  }

  __syncthreads();   // hT + yxa ready

  // ---- out GEMM: A = h bf16 [t][s], B = Wout (this wave's 2 d-slices) ----
  floatx4 Oc[2][4];
#pragma unroll
  for (int ntl = 0; ntl < 2; ++ntl)
#pragma unroll
    for (int mt = 0; mt < 4; ++mt) Oc[ntl][mt] = (floatx4){0.f, 0.f, 0.f, 0.f};
#pragma unroll
  for (int kk = 0; kk < 4; ++kk) {
    bf16x8 fO0 = WFRAG(3, 2 * w + 0, kk);
    bf16x8 fO1 = WFRAG(3, 2 * w + 1, kk);
#pragma unroll
    for (int mt = 0; mt < 4; ++mt) {
      bf16x8 h = *(const bf16x8*)&xb[(16 * mt + c) * XSTR + 8 * g + 32 * kk];
      Oc[0][mt] = __builtin_amdgcn_mfma_f32_16x16x32_bf16(h, fO0, Oc[0][mt], 0, 0, 0);
      Oc[1][mt] = __builtin_amdgcn_mfma_f32_16x16x32_bf16(h, fO1, Oc[1][mt], 0, 0, 0);
    }
  }

  // ---- epilogue: y folded here (no extra barrier / serial phase) ----
#pragma unroll
  for (int mt = 0; mt < 4; ++mt)
#pragma unroll
    for (int i = 0; i < 4; ++i) {
      int row = 16 * mt + 4 * g + i;
      float yt = (yxa[row] + yxa[64 + row] + yxa[128 + row] + yxa[192 + row]) * x0s[row];
#pragma unroll
      for (int ntl = 0; ntl < 2; ++ntl)
        out[(chunk_t0 + row) * D_ + 32 * w + 16 * ntl + c] = Oc[ntl][mt][i] + yt;
    }
}

extern "C" void kernel_launch(void* const* d_in, const int* in_sizes, int n_in,
                              void* d_out, int out_size, void* d_ws, size_t ws_size,
                              hipStream_t stream) {
  const float* x    = (const float*)d_in[0];
  const float* logA = (const float*)d_in[1];
  const float* W_B  = (const float*)d_in[2];
  const float* W_C  = (const float*)d_in[3];
  const float* W_dt = (const float*)d_in[4];
  const float* b_dt = (const float*)d_in[5];
  const float* W_out= (const float*)d_in[6];
  float* out = (float*)d_out;
  float* ws  = (float*)d_ws;

  k0_prep<<<64, 256, 0, stream>>>(W_dt, W_B, W_C, W_out, logA, ws);
  k_main<<<NCHUNK, 256, 0, stream>>>(x, b_dt, out, ws);
}